// Round 10
// baseline (824.649 us; speedup 1.0000x reference)
//
#include <hip/hip_runtime.h>
#include <hip/hip_fp16.h>

typedef __attribute__((ext_vector_type(8))) _Float16 half8;
typedef __attribute__((ext_vector_type(4))) _Float16 half4;
typedef __attribute__((ext_vector_type(4))) float float4v;

#define NPIX 16384  // 128*128

__device__ inline half8 h8zero() {
    half8 z = {(_Float16)0, (_Float16)0, (_Float16)0, (_Float16)0,
               (_Float16)0, (_Float16)0, (_Float16)0, (_Float16)0};
    return z;
}

// ---------------- all weight packing + head conv in ONE dispatch ----------------
__global__ void pack_all(const float* __restrict__ rb_w, const float* __restrict__ tail_w,
                         const float* __restrict__ mw0, const float* __restrict__ mw1,
                         const float* __restrict__ mw2, const float* __restrict__ mw3,
                         const float* __restrict__ mw4, const float* __restrict__ mb0,
                         const float* __restrict__ x, const float* __restrict__ head_w,
                         const float* __restrict__ head_b,
                         _Float16* __restrict__ pwc, _Float16* __restrict__ pw0,
                         _Float16* __restrict__ pwm, float* __restrict__ b0p,
                         _Float16* __restrict__ h0) {
    int idx = blockIdx.x * 256 + threadIdx.x;
    if (idx < 1216512) {                      // conv weights -> B-frag order
        int ci = idx / 36864;
        int e  = idx % 36864;
        int j = e & 7, ln = (e >> 3) & 63, kcnt = e >> 9;
        int kc = kcnt % 18, ntc = kcnt / 18;
        int k = kc * 32 + (ln >> 4) * 8 + j;
        int nn = ntc * 16 + (ln & 15);
        int ij = k >> 6, c = k & 63;
        const float* src = (ci < 32) ? (rb_w + ci * 36864) : tail_w;
        pwc[idx] = (_Float16)src[(nn * 64 + c) * 9 + ij];
        return;
    }
    idx -= 1216512;
    if (idx < 147456) {                       // mw0[:576] pack (N=256)
        int j = idx & 7, ln = (idx >> 3) & 63, kcnt = idx >> 9;
        int kc = kcnt % 18, ntc = kcnt / 18;
        int k = kc * 32 + (ln >> 4) * 8 + j;
        int nn = ntc * 16 + (ln & 15);
        int ij = k >> 6, c = k & 63;
        pw0[idx] = (_Float16)mw0[(c * 9 + ij) * 256 + nn];
        return;
    }
    idx -= 147456;
    if (idx < 200704) {                       // mlp hidden + padded mw4
        if (idx < 196608) {
            int l = idx / 65536;
            int e = idx % 65536;
            int j = e & 7, ln = (e >> 3) & 63, kcnt = e >> 9;
            int kc = kcnt & 7, ntc = kcnt >> 3;
            int k = kc * 32 + (ln >> 4) * 8 + j;
            int nn = ntc * 16 + (ln & 15);
            const float* w = (l == 0) ? mw1 : ((l == 1) ? mw2 : mw3);
            pwm[idx] = (_Float16)w[k * 256 + nn];
        } else {
            int e = idx - 196608;
            int j = e & 7, ln = (e >> 3) & 63, kc = e >> 9;
            int k = kc * 32 + (ln >> 4) * 8 + j;
            int nn = ln & 15;
            pwm[idx] = (nn < 3) ? (_Float16)mw4[k * 3 + nn] : (_Float16)0.0f;
        }
        return;
    }
    idx -= 200704;
    if (idx < 256) {
        b0p[idx] = mb0[idx] + 0.5f * (mw0[578 * 256 + idx] + mw0[579 * 256 + idx]);
        return;
    }
    idx -= 256;
    if (idx < NPIX * 64) {                    // head conv (Cin=3, direct fp32)
        int o = idx & 63, p = idx >> 6;
        int py = p >> 7, px = p & 127;
        float acc = head_b[o];
        #pragma unroll
        for (int c = 0; c < 3; ++c)
            #pragma unroll
            for (int i = 0; i < 3; ++i)
                #pragma unroll
                for (int jj = 0; jj < 3; ++jj) {
                    int y = py + i - 1, xx = px + jj - 1;
                    if (y >= 0 && y < 128 && xx >= 0 && xx < 128)
                        acc += x[c * 16384 + y * 128 + xx]
                             * head_w[((o * 3 + c) * 3 + i) * 3 + jj];
                }
        h0[idx] = (_Float16)acc;
    }
}

// ---------------- fused 2-resblock kernel ----------------
#define LDS_STRIDE 72

template <int DH, int DW, int SW, int SOFF, int RES>
__device__ __forceinline__ void conv_stage(
    const _Float16* __restrict__ src, _Float16* __restrict__ dst, _Float16* __restrict__ INb,
    const _Float16* __restrict__ pw, const float* __restrict__ bias,
    int q, int r, int nb, int gy0, int gx0, _Float16* __restrict__ gout)
{
    half8 B[18];
    #pragma unroll
    for (int kc = 0; kc < 18; ++kc)
        B[kc] = *(const half8*)(pw + ((((nb >> 4) * 18 + kc) * 64 + (q << 4) + r) << 3));
    float bv = bias[nb + r];
    constexpr int NPXc = DH * DW;
    constexpr int NT = (NPXc + 15) >> 4;
    #pragma unroll 1
    for (int tl = 0; tl < NT; ++tl) {
        int pa = tl * 16 + r;
        int ca = pa < NPXc ? pa : NPXc - 1;
        int my = ca / DW, mx = ca % DW;
        float4v acc = {0.f, 0.f, 0.f, 0.f};
        #pragma unroll
        for (int kc = 0; kc < 18; ++kc) {
            int ij = kc >> 1;
            int di = ij / 3 - 1;
            int dj = ij % 3 - 1;
            int cb = ((kc & 1) << 5) + (q << 3);
            int sp = (my + 1 + di + SOFF) * SW + (mx + 1 + dj + SOFF);
            half8 a = *(const half8*)(src + sp * LDS_STRIDE + cb);
            acc = __builtin_amdgcn_mfma_f32_16x16x32_f16(a, B[kc], acc, 0, 0, 0);
        }
        #pragma unroll
        for (int reg = 0; reg < 4; ++reg) {
            int pc = tl * 16 + (q << 2) + reg;
            if (pc >= NPXc) continue;
            int dy = pc / DW, dx = pc % DW;
            int gy = gy0 + dy, gx = gx0 + dx;
            bool valid = (gy >= 0 && gy < 128 && gx >= 0 && gx < 128);
            if (RES == 0) {
                float v = fmaxf(acc[reg] + bv, 0.f);
                dst[pc * LDS_STRIDE + nb + r] = valid ? (_Float16)v : (_Float16)0.0f;
            } else if (RES == 1) {
                int sl = ((dy + 2) * 16 + dx + 2) * LDS_STRIDE + nb + r;
                float v = acc[reg] + bv + (float)INb[sl];
                INb[sl] = valid ? (_Float16)v : (_Float16)0.0f;
            } else {
                int sl = ((dy + 4) * 16 + dx + 4) * LDS_STRIDE + nb + r;
                float v = acc[reg] + bv + (float)INb[sl];
                gout[(((gy << 7) + gx) << 6) + nb + r] = (_Float16)v;
            }
        }
    }
}

__global__ __launch_bounds__(256, 3)
void rb_pair(const _Float16* __restrict__ img, const _Float16* __restrict__ pw,
             const float* __restrict__ bias, _Float16* __restrict__ out) {
    __shared__ _Float16 IN[192 * LDS_STRIDE];
    __shared__ _Float16 MID[140 * LDS_STRIDE];
    int t = threadIdx.x;
    int wave = t >> 6, lane = t & 63, q = lane >> 4, r = lane & 15;
    int tr = blockIdx.x >> 4, tc = blockIdx.x & 15;
    int ty0 = tr << 2, tx0 = tc << 3;
    int nb = wave << 4;

    #pragma unroll
    for (int i = 0; i < 6; ++i) {
        int idx = t + i * 256;
        int px = idx >> 3, c = idx & 7;
        int iy = px >> 4, ix = px & 15;
        int gy = ty0 - 4 + iy, gx = tx0 - 4 + ix;
        half8 v = h8zero();
        if (gy >= 0 && gy < 128 && gx >= 0 && gx < 128)
            v = *(const half8*)(img + (((gy << 7) + gx) << 6) + (c << 3));
        *(half8*)(IN + px * LDS_STRIDE + (c << 3)) = v;
    }
    __syncthreads();

    conv_stage<10, 14, 16, 0, 0>(IN, MID, IN, pw, bias, q, r, nb, ty0 - 3, tx0 - 3, nullptr);
    __syncthreads();
    conv_stage<8, 12, 14, 0, 1>(MID, nullptr, IN, pw + 36864, bias + 64, q, r, nb,
                                ty0 - 2, tx0 - 2, nullptr);
    __syncthreads();
    conv_stage<6, 10, 16, 2, 0>(IN, MID, IN, pw + 2 * 36864, bias + 128, q, r, nb,
                                ty0 - 1, tx0 - 1, nullptr);
    __syncthreads();
    conv_stage<4, 8, 10, 0, 2>(MID, nullptr, IN, pw + 3 * 36864, bias + 192, q, r, nb,
                               ty0, tx0, out);
}

// ---------------- unfused conv (tail + stage-A) ----------
template <int NTOT, int MTPER, bool RELU, bool RES, bool F32OUT>
__global__ __launch_bounds__(256, 2)
void conv_mfma_r(const _Float16* __restrict__ img, const _Float16* __restrict__ pw,
                 const float* __restrict__ bias, const _Float16* res,
                 _Float16* outh, float* outf) {
    int wave = threadIdx.x >> 6, lane = threadIdx.x & 63;
    int q = lane >> 4, r = lane & 15;
    int nt, mt0;
    if constexpr (NTOT == 4) {
        nt = wave;
        mt0 = blockIdx.x * MTPER;
    } else {
        nt = (blockIdx.x & 3) * 4 + wave;
        mt0 = (blockIdx.x >> 2) * MTPER;
    }
    half8 B[18];
    #pragma unroll
    for (int kc = 0; kc < 18; ++kc)
        B[kc] = *(const half8*)(pw + (((nt * 18 + kc) * 64 + lane) << 3));
    int n = nt * 16 + r;
    float bv = bias[n];
    #pragma unroll
    for (int mi = 0; mi < MTPER; ++mi) {
        int mt = mt0 + mi;
        int p0 = mt * 16;
        int py = p0 >> 7;
        int pxl = (p0 & 127) + r;
        float4v acc = {0.f, 0.f, 0.f, 0.f};
        #pragma unroll
        for (int kc = 0; kc < 18; ++kc) {
            int ij = kc >> 1;
            int di = ij / 3 - 1;
            int dj = ij % 3 - 1;
            int cb = ((kc & 1) << 5) + (q << 3);
            int yy = py + di, xx = pxl + dj;
            half8 a = h8zero();
            if (yy >= 0 && yy < 128 && xx >= 0 && xx < 128)
                a = *(const half8*)(img + (((yy << 7) + xx) << 6) + cb);
            acc = __builtin_amdgcn_mfma_f32_16x16x32_f16(a, B[kc], acc, 0, 0, 0);
        }
        #pragma unroll
        for (int reg = 0; reg < 4; ++reg) {
            int p = p0 + (q << 2) + reg;
            float v = acc[reg] + bv;
            if (RES) v += (float)res[p * (NTOT * 16) + n];
            if (RELU) v = fmaxf(v, 0.f);
            if (F32OUT) outf[p * (NTOT * 16) + n] = v;
            else        outh[p * (NTOT * 16) + n] = (_Float16)v;
        }
    }
}

// ---------------- fused LIIF MLP + ensembling (16 px, transposed hidden) --------
// Block: 256 thr (4 waves) = 16 output pixels = 64 samples.
// act LDS layout is fragment-major and ROLE-SYMMETRIC: chunk (X*8+kc)*64 + q*16+r
// holds entity X*16+r, dim2 elements kc*32+q*8..+8.
// launch_bounds(256,4): cap arch VGPR at 64. gfx950's unified VGPR/AGPR file means
// 64 arch + 64 acc = 128 total -> 4 waves/SIMD (R4's proven occupancy point).
// To FIT the 64 cap without spilling (R8's failure): A (weight) fragment is loaded
// ONE at a time inside the mti loop (live 4 VGPR, not 16), and bias is loaded
// per-mti in the epilogue (live 4 VGPR, outside the MFMA region).
__global__ __launch_bounds__(256, 4)
void mlp_kernel(const float* __restrict__ apre, const float* __restrict__ mw0,
                const float* __restrict__ mb1, const float* __restrict__ mb2,
                const float* __restrict__ mb3, const float* __restrict__ mb4,
                const _Float16* __restrict__ pwm, const _Float16* __restrict__ pw4,
                float* __restrict__ out) {
    __shared__ _Float16 act[16384];        // 64 x 256, fragment-major (32 KB)
    __shared__ float sArea[64], sRelH[64], sRelW[64];
    __shared__ int sCell[64];
    __shared__ float sWh[256], sWw[256];

    int t = threadIdx.x;
    int bid = blockIdx.x;
    int logical = (bid & 7) * 2048 + (bid >> 3);   // XCD-contiguous pixel strips
    int p0 = logical << 4;

    if (t < 64) {
        int lp = t >> 2, rc = t & 3;
        int p = p0 + lp;
        int oh = p >> 9, ow = p & 511;
        float sh = (oh + 0.5f) * (2.0f / 512.0f) - 1.0f;
        float sw = (ow + 0.5f) * (2.0f / 512.0f) - 1.0f;
        float gh = sh + (((rc >> 1) != 0) ? (1.0f / 128.0f) : (-1.0f / 128.0f));
        float gw = sw + (((rc & 1) != 0) ? (1.0f / 128.0f) : (-1.0f / 128.0f));
        const float lim = 1.0f - 1e-6f;
        gh = fminf(fmaxf(gh, -lim), lim);
        gw = fminf(fmaxf(gw, -lim), lim);
        int iy = (int)rintf(((gh + 1.0f) * 128.0f - 1.0f) * 0.5f);  // round-half-even
        int ix = (int)rintf(((gw + 1.0f) * 128.0f - 1.0f) * 0.5f);
        iy = iy < 0 ? 0 : (iy > 127 ? 127 : iy);
        ix = ix < 0 ? 0 : (ix > 127 ? 127 : ix);
        float cy = (iy + 0.5f) * (2.0f / 128.0f) - 1.0f;
        float cx = (ix + 0.5f) * (2.0f / 128.0f) - 1.0f;
        float rh = (sh - cy) * 128.0f;
        float rw = (sw - cx) * 128.0f;
        sCell[t] = (iy << 7) + ix;
        sRelH[t] = rh; sRelW[t] = rw;
        sArea[t] = fabsf(rh * rw);
    }
    sWh[t] = mw0[576 * 256 + t];
    sWw[t] = mw0[577 * 256 + t];
    __syncthreads();

    int wave = t >> 6, lane = t & 63, q = lane >> 4, r = lane & 15;

    // layer 1: lane-linear staging. Thread handles sample s = wave*16 + r,
    // features f = j*32 + q*8 .. +8; write chunk (wave*8+j)*64 + lane.
    {
        int s = (wave << 4) + r;
        float rh = sRelH[s], rw = sRelW[s];
        const float* ap = apre + ((size_t)sCell[s] << 8) + (q << 3);
        #pragma unroll
        for (int j = 0; j < 8; ++j) {
            int f0 = (j << 5) + (q << 3);
            float4v lo = *(const float4v*)(ap + (j << 5));
            float4v hi = *(const float4v*)(ap + (j << 5) + 4);
            half8 hv;
            #pragma unroll
            for (int kk = 0; kk < 4; ++kk) {
                float v = lo[kk] + rh * sWh[f0 + kk] + rw * sWw[f0 + kk];
                hv[kk] = (_Float16)fmaxf(v, 0.0f);
            }
            #pragma unroll
            for (int kk = 0; kk < 4; ++kk) {
                float v = hi[kk] + rh * sWh[f0 + 4 + kk] + rw * sWw[f0 + 4 + kk];
                hv[4 + kk] = (_Float16)fmaxf(v, 0.0f);
            }
            *(half8*)(act + ((((wave << 3) + j) * 64 + lane) << 3)) = hv;
        }
    }
    __syncthreads();

    // hidden layers (transposed): wave owns out-features [wave*64, +64) x 64 samples
    float4v acc[4][4];
    #pragma unroll 1
    for (int l = 0; l < 3; ++l) {
        #pragma unroll
        for (int mti = 0; mti < 4; ++mti)
            #pragma unroll
            for (int nts = 0; nts < 4; ++nts)
                acc[mti][nts] = (float4v){0.f, 0.f, 0.f, 0.f};
        const _Float16* pw = pwm + l * 65536;
        for (int kc = 0; kc < 8; ++kc) {
            half8 Bf[4];
            #pragma unroll
            for (int nts = 0; nts < 4; ++nts)
                Bf[nts] = *(const half8*)(act + ((((nts << 3) + kc) * 64 + lane) << 3));
            #pragma unroll
            for (int mti = 0; mti < 4; ++mti) {
                half8 A = *(const half8*)(pw + ((((wave * 4 + mti) * 8 + kc) * 64 + lane) << 3));
                #pragma unroll
                for (int nts = 0; nts < 4; ++nts)
                    acc[mti][nts] = __builtin_amdgcn_mfma_f32_16x16x32_f16(
                        A, Bf[nts], acc[mti][nts], 0, 0, 0);
            }
        }
        const float* mb = (l == 0) ? mb1 : ((l == 1) ? mb2 : mb3);
        __syncthreads();   // all waves done reading act
        #pragma unroll
        for (int mti = 0; mti < 4; ++mti) {
            float4v bvv = *(const float4v*)(mb + (wave << 6) + mti * 16 + (q << 2));
            #pragma unroll
            for (int nts = 0; nts < 4; ++nts) {
                // feature f = wave*64 + mti*16 + q*4 + reg, sample s = nts*16 + r
                int base = ((((nts << 3) + (wave << 1) + (mti >> 1)) * 64
                             + (((mti & 1) * 2 + (q >> 1)) << 4) + r) << 3) + ((q & 1) << 2);
                half4 hv;
                #pragma unroll
                for (int reg = 0; reg < 4; ++reg)
                    hv[reg] = (_Float16)fmaxf(acc[mti][nts][reg] + bvv[reg], 0.0f);
                *(half4*)(act + base) = hv;
            }
        }
        __syncthreads();
    }

    // final layer: M=16 (3 real channels), wave w handles samples [w*16, w*16+16)
    float4v af = {0.f, 0.f, 0.f, 0.f};
    #pragma unroll
    for (int kc = 0; kc < 8; ++kc) {
        half8 A = *(const half8*)(pw4 + ((kc * 64 + lane) << 3));
        half8 Bf = *(const half8*)(act + ((((wave << 3) + kc) * 64 + lane) << 3));
        af = __builtin_amdgcn_mfma_f32_16x16x32_f16(A, Bf, af, 0, 0, 0);
    }
    // lane (q=0, r): af[reg] = pred[ch=reg][sample = wave*16 + r]
    int s = (wave << 4) + r;
    int lp = s >> 2, rc = s & 3;
    float ar = sArea[(lp << 2) + (3 - rc)];    // LIIF diagonal-swapped area
    float c0 = (af[0] + mb4[0]) * ar;
    float c1 = (af[1] + mb4[1]) * ar;
    float c2 = (af[2] + mb4[2]) * ar;
    c0 += __shfl_xor(c0, 1); c1 += __shfl_xor(c1, 1); c2 += __shfl_xor(c2, 1);
    float at = ar + __shfl_xor(ar, 1);
    c0 += __shfl_xor(c0, 2); c1 += __shfl_xor(c1, 2); c2 += __shfl_xor(c2, 2);
    at += __shfl_xor(at, 2);
    if (q == 0 && rc == 0) {
        float inv = 1.0f / (at + 1e-9f);
        out[p0 + lp]          = fminf(fmaxf(c0 * inv, 0.0f), 1.0f);
        out[262144 + p0 + lp] = fminf(fmaxf(c1 * inv, 0.0f), 1.0f);
        out[524288 + p0 + lp] = fminf(fmaxf(c2 * inv, 0.0f), 1.0f);
    }
}

extern "C" void kernel_launch(void* const* d_in, const int* in_sizes, int n_in,
                              void* d_out, int out_size, void* d_ws, size_t ws_size,
                              hipStream_t stream) {
    (void)in_sizes; (void)n_in; (void)out_size; (void)ws_size;
    const float* x      = (const float*)d_in[0];
    const float* head_w = (const float*)d_in[2];
    const float* head_b = (const float*)d_in[3];
    const float* rb_w   = (const float*)d_in[4];
    const float* rb_b   = (const float*)d_in[5];
    const float* tail_w = (const float*)d_in[6];
    const float* tail_b = (const float*)d_in[7];
    const float* mw0    = (const float*)d_in[8];
    const float* mb0    = (const float*)d_in[9];
    const float* mw1    = (const float*)d_in[10];
    const float* mb1    = (const float*)d_in[11];
    const float* mw2    = (const float*)d_in[12];
    const float* mb2    = (const float*)d_in[13];
    const float* mw3    = (const float*)d_in[14];
    const float* mb3    = (const float*)d_in[15];
    const float* mw4    = (const float*)d_in[16];
    const float* mb4    = (const float*)d_in[17];
    float* out = (float*)d_out;

    char* w = (char*)d_ws;
    auto take = [&](size_t n) { char* p = w; w += (n + 255) & ~(size_t)255; return p; };
    _Float16* pwc  = (_Float16*)take(33u * 36864u * 2u);
    _Float16* pw0  = (_Float16*)take(147456u * 2u);
    _Float16* pwm  = (_Float16*)take(200704u * 2u);
    float*    b0p  = (float*)take(256u * 4u);
    _Float16* h0   = (_Float16*)take((size_t)NPIX * 64u * 2u);
    _Float16* hbuf = (_Float16*)take((size_t)NPIX * 64u * 2u);
    _Float16* tbuf = (_Float16*)take((size_t)NPIX * 64u * 2u);
    _Float16* feat = (_Float16*)take((size_t)NPIX * 64u * 2u);
    float*    apre = (float*)take((size_t)NPIX * 256u * 4u);

    pack_all<<<10209, 256, 0, stream>>>(rb_w, tail_w, mw0, mw1, mw2, mw3, mw4, mb0,
                                        x, head_w, head_b, pwc, pw0, pwm, b0p, h0);

    const _Float16* cur = h0;
    for (int p = 0; p < 8; ++p) {
        _Float16* dst = (p & 1) ? tbuf : hbuf;
        rb_pair<<<512, 256, 0, stream>>>(cur, pwc + 4 * p * 36864, rb_b + p * 256, dst);
        cur = dst;
    }
    conv_mfma_r<4, 2, false, true, false><<<512, 256, 0, stream>>>(
        cur, pwc + 32 * 36864, tail_b, h0, feat, nullptr);
    conv_mfma_r<16, 4, false, false, true><<<1024, 256, 0, stream>>>(
        feat, pw0, b0p, nullptr, nullptr, apre);

    mlp_kernel<<<16384, 256, 0, stream>>>(apre, mw0, mb1, mb2, mb3, mb4,
                                          pwm, pwm + 196608, out);
}

// Round 11
// 812.458 us; speedup vs baseline: 1.0150x; 1.0150x over previous
//
#include <hip/hip_runtime.h>
#include <hip/hip_fp16.h>

typedef __attribute__((ext_vector_type(8))) _Float16 half8;
typedef __attribute__((ext_vector_type(4))) _Float16 half4;
typedef __attribute__((ext_vector_type(4))) float float4v;

#define NPIX 16384  // 128*128

__device__ inline half8 h8zero() {
    half8 z = {(_Float16)0, (_Float16)0, (_Float16)0, (_Float16)0,
               (_Float16)0, (_Float16)0, (_Float16)0, (_Float16)0};
    return z;
}

// ---------------- all weight packing + head conv in ONE dispatch ----------------
__global__ void pack_all(const float* __restrict__ rb_w, const float* __restrict__ tail_w,
                         const float* __restrict__ mw0, const float* __restrict__ mw1,
                         const float* __restrict__ mw2, const float* __restrict__ mw3,
                         const float* __restrict__ mw4, const float* __restrict__ mb0,
                         const float* __restrict__ x, const float* __restrict__ head_w,
                         const float* __restrict__ head_b,
                         _Float16* __restrict__ pwc, _Float16* __restrict__ pw0,
                         _Float16* __restrict__ pwm, float* __restrict__ b0p,
                         _Float16* __restrict__ h0) {
    int idx = blockIdx.x * 256 + threadIdx.x;
    if (idx < 1216512) {                      // conv weights -> B-frag order
        int ci = idx / 36864;
        int e  = idx % 36864;
        int j = e & 7, ln = (e >> 3) & 63, kcnt = e >> 9;
        int kc = kcnt % 18, ntc = kcnt / 18;
        int k = kc * 32 + (ln >> 4) * 8 + j;
        int nn = ntc * 16 + (ln & 15);
        int ij = k >> 6, c = k & 63;
        const float* src = (ci < 32) ? (rb_w + ci * 36864) : tail_w;
        pwc[idx] = (_Float16)src[(nn * 64 + c) * 9 + ij];
        return;
    }
    idx -= 1216512;
    if (idx < 147456) {                       // mw0[:576] pack (N=256)
        int j = idx & 7, ln = (idx >> 3) & 63, kcnt = idx >> 9;
        int kc = kcnt % 18, ntc = kcnt / 18;
        int k = kc * 32 + (ln >> 4) * 8 + j;
        int nn = ntc * 16 + (ln & 15);
        int ij = k >> 6, c = k & 63;
        pw0[idx] = (_Float16)mw0[(c * 9 + ij) * 256 + nn];
        return;
    }
    idx -= 147456;
    if (idx < 200704) {                       // mlp hidden + padded mw4
        if (idx < 196608) {
            int l = idx / 65536;
            int e = idx % 65536;
            int j = e & 7, ln = (e >> 3) & 63, kcnt = e >> 9;
            int kc = kcnt & 7, ntc = kcnt >> 3;
            int k = kc * 32 + (ln >> 4) * 8 + j;
            int nn = ntc * 16 + (ln & 15);
            const float* w = (l == 0) ? mw1 : ((l == 1) ? mw2 : mw3);
            pwm[idx] = (_Float16)w[k * 256 + nn];
        } else {
            int e = idx - 196608;
            int j = e & 7, ln = (e >> 3) & 63, kc = e >> 9;
            int k = kc * 32 + (ln >> 4) * 8 + j;
            int nn = ln & 15;
            pwm[idx] = (nn < 3) ? (_Float16)mw4[k * 3 + nn] : (_Float16)0.0f;
        }
        return;
    }
    idx -= 200704;
    if (idx < 256) {
        b0p[idx] = mb0[idx] + 0.5f * (mw0[578 * 256 + idx] + mw0[579 * 256 + idx]);
        return;
    }
    idx -= 256;
    if (idx < NPIX * 64) {                    // head conv (Cin=3, direct fp32)
        int o = idx & 63, p = idx >> 6;
        int py = p >> 7, px = p & 127;
        float acc = head_b[o];
        #pragma unroll
        for (int c = 0; c < 3; ++c)
            #pragma unroll
            for (int i = 0; i < 3; ++i)
                #pragma unroll
                for (int jj = 0; jj < 3; ++jj) {
                    int y = py + i - 1, xx = px + jj - 1;
                    if (y >= 0 && y < 128 && xx >= 0 && xx < 128)
                        acc += x[c * 16384 + y * 128 + xx]
                             * head_w[((o * 3 + c) * 3 + i) * 3 + jj];
                }
        h0[idx] = (_Float16)acc;
    }
}

// ---------------- fused 2-resblock kernel ----------------
#define LDS_STRIDE 72

template <int DH, int DW, int SW, int SOFF, int RES>
__device__ __forceinline__ void conv_stage(
    const _Float16* __restrict__ src, _Float16* __restrict__ dst, _Float16* __restrict__ INb,
    const _Float16* __restrict__ pw, const float* __restrict__ bias,
    int q, int r, int nb, int gy0, int gx0, _Float16* __restrict__ gout)
{
    half8 B[18];
    #pragma unroll
    for (int kc = 0; kc < 18; ++kc)
        B[kc] = *(const half8*)(pw + ((((nb >> 4) * 18 + kc) * 64 + (q << 4) + r) << 3));
    float bv = bias[nb + r];
    constexpr int NPXc = DH * DW;
    constexpr int NT = (NPXc + 15) >> 4;
    #pragma unroll 1
    for (int tl = 0; tl < NT; ++tl) {
        int pa = tl * 16 + r;
        int ca = pa < NPXc ? pa : NPXc - 1;
        int my = ca / DW, mx = ca % DW;
        float4v acc = {0.f, 0.f, 0.f, 0.f};
        #pragma unroll
        for (int kc = 0; kc < 18; ++kc) {
            int ij = kc >> 1;
            int di = ij / 3 - 1;
            int dj = ij % 3 - 1;
            int cb = ((kc & 1) << 5) + (q << 3);
            int sp = (my + 1 + di + SOFF) * SW + (mx + 1 + dj + SOFF);
            half8 a = *(const half8*)(src + sp * LDS_STRIDE + cb);
            acc = __builtin_amdgcn_mfma_f32_16x16x32_f16(a, B[kc], acc, 0, 0, 0);
        }
        #pragma unroll
        for (int reg = 0; reg < 4; ++reg) {
            int pc = tl * 16 + (q << 2) + reg;
            if (pc >= NPXc) continue;
            int dy = pc / DW, dx = pc % DW;
            int gy = gy0 + dy, gx = gx0 + dx;
            bool valid = (gy >= 0 && gy < 128 && gx >= 0 && gx < 128);
            if (RES == 0) {
                float v = fmaxf(acc[reg] + bv, 0.f);
                dst[pc * LDS_STRIDE + nb + r] = valid ? (_Float16)v : (_Float16)0.0f;
            } else if (RES == 1) {
                int sl = ((dy + 2) * 16 + dx + 2) * LDS_STRIDE + nb + r;
                float v = acc[reg] + bv + (float)INb[sl];
                INb[sl] = valid ? (_Float16)v : (_Float16)0.0f;
            } else {
                int sl = ((dy + 4) * 16 + dx + 4) * LDS_STRIDE + nb + r;
                float v = acc[reg] + bv + (float)INb[sl];
                gout[(((gy << 7) + gx) << 6) + nb + r] = (_Float16)v;
            }
        }
    }
}

__global__ __launch_bounds__(256, 3)
void rb_pair(const _Float16* __restrict__ img, const _Float16* __restrict__ pw,
             const float* __restrict__ bias, _Float16* __restrict__ out) {
    __shared__ _Float16 IN[192 * LDS_STRIDE];
    __shared__ _Float16 MID[140 * LDS_STRIDE];
    int t = threadIdx.x;
    int wave = t >> 6, lane = t & 63, q = lane >> 4, r = lane & 15;
    int tr = blockIdx.x >> 4, tc = blockIdx.x & 15;
    int ty0 = tr << 2, tx0 = tc << 3;
    int nb = wave << 4;

    #pragma unroll
    for (int i = 0; i < 6; ++i) {
        int idx = t + i * 256;
        int px = idx >> 3, c = idx & 7;
        int iy = px >> 4, ix = px & 15;
        int gy = ty0 - 4 + iy, gx = tx0 - 4 + ix;
        half8 v = h8zero();
        if (gy >= 0 && gy < 128 && gx >= 0 && gx < 128)
            v = *(const half8*)(img + (((gy << 7) + gx) << 6) + (c << 3));
        *(half8*)(IN + px * LDS_STRIDE + (c << 3)) = v;
    }
    __syncthreads();

    conv_stage<10, 14, 16, 0, 0>(IN, MID, IN, pw, bias, q, r, nb, ty0 - 3, tx0 - 3, nullptr);
    __syncthreads();
    conv_stage<8, 12, 14, 0, 1>(MID, nullptr, IN, pw + 36864, bias + 64, q, r, nb,
                                ty0 - 2, tx0 - 2, nullptr);
    __syncthreads();
    conv_stage<6, 10, 16, 2, 0>(IN, MID, IN, pw + 2 * 36864, bias + 128, q, r, nb,
                                ty0 - 1, tx0 - 1, nullptr);
    __syncthreads();
    conv_stage<4, 8, 10, 0, 2>(MID, nullptr, IN, pw + 3 * 36864, bias + 192, q, r, nb,
                               ty0, tx0, out);
}

// ---------------- unfused conv (tail + stage-A) ----------
template <int NTOT, int MTPER, bool RELU, bool RES, bool F32OUT>
__global__ __launch_bounds__(256, 2)
void conv_mfma_r(const _Float16* __restrict__ img, const _Float16* __restrict__ pw,
                 const float* __restrict__ bias, const _Float16* res,
                 _Float16* outh, float* outf) {
    int wave = threadIdx.x >> 6, lane = threadIdx.x & 63;
    int q = lane >> 4, r = lane & 15;
    int nt, mt0;
    if constexpr (NTOT == 4) {
        nt = wave;
        mt0 = blockIdx.x * MTPER;
    } else {
        nt = (blockIdx.x & 3) * 4 + wave;
        mt0 = (blockIdx.x >> 2) * MTPER;
    }
    half8 B[18];
    #pragma unroll
    for (int kc = 0; kc < 18; ++kc)
        B[kc] = *(const half8*)(pw + (((nt * 18 + kc) * 64 + lane) << 3));
    int n = nt * 16 + r;
    float bv = bias[n];
    #pragma unroll
    for (int mi = 0; mi < MTPER; ++mi) {
        int mt = mt0 + mi;
        int p0 = mt * 16;
        int py = p0 >> 7;
        int pxl = (p0 & 127) + r;
        float4v acc = {0.f, 0.f, 0.f, 0.f};
        #pragma unroll
        for (int kc = 0; kc < 18; ++kc) {
            int ij = kc >> 1;
            int di = ij / 3 - 1;
            int dj = ij % 3 - 1;
            int cb = ((kc & 1) << 5) + (q << 3);
            int yy = py + di, xx = pxl + dj;
            half8 a = h8zero();
            if (yy >= 0 && yy < 128 && xx >= 0 && xx < 128)
                a = *(const half8*)(img + (((yy << 7) + xx) << 6) + cb);
            acc = __builtin_amdgcn_mfma_f32_16x16x32_f16(a, B[kc], acc, 0, 0, 0);
        }
        #pragma unroll
        for (int reg = 0; reg < 4; ++reg) {
            int p = p0 + (q << 2) + reg;
            float v = acc[reg] + bv;
            if (RES) v += (float)res[p * (NTOT * 16) + n];
            if (RELU) v = fmaxf(v, 0.f);
            if (F32OUT) outf[p * (NTOT * 16) + n] = v;
            else        outh[p * (NTOT * 16) + n] = (_Float16)v;
        }
    }
}

// ---------------- fused LIIF MLP + ensembling (16 px, 8-wave transposed) --------
// Block: 512 thr (8 waves) = 16 output pixels = 64 samples.
// Transposed MFMA: M = out-features, N = samples. Wave w owns features
// [w*32, w*32+32) (mti 0..1) x all 64 samples -> acc[2][4] = 32 AGPR/thread.
// With arch VGPR ~88 (R9 measurement) total ~120 <= 128 -> 4 waves/SIMD
// (16 waves/CU, R4's occupancy) WITHOUT spill (R10's cap-64 spilled 175 MB).
// launch_bounds(512,4): arch cap 128.
// act LDS fragment-major: chunk X (eg=X>>3, kc=X&7), lane (q,r), elem e holds
// entity eg*16+r, element kc*32+q*8+e. Role-symmetric for A/B operands.
__global__ __launch_bounds__(512, 4)
void mlp_kernel(const float* __restrict__ apre, const float* __restrict__ mw0,
                const float* __restrict__ mb1, const float* __restrict__ mb2,
                const float* __restrict__ mb3, const float* __restrict__ mb4,
                const _Float16* __restrict__ pwm, const _Float16* __restrict__ pw4,
                float* __restrict__ out) {
    __shared__ _Float16 act[16384];        // 64 samples x 256 features (32 KB)
    __shared__ float sArea[64], sRelH[64], sRelW[64];
    __shared__ int sCell[64];
    __shared__ float sWh[256], sWw[256];

    int t = threadIdx.x;
    int bid = blockIdx.x;
    int logical = (bid & 7) * 2048 + (bid >> 3);   // XCD-contiguous pixel strips
    int p0 = logical << 4;

    if (t < 64) {
        int lp = t >> 2, rc = t & 3;
        int p = p0 + lp;
        int oh = p >> 9, ow = p & 511;
        float sh = (oh + 0.5f) * (2.0f / 512.0f) - 1.0f;
        float sw = (ow + 0.5f) * (2.0f / 512.0f) - 1.0f;
        float gh = sh + (((rc >> 1) != 0) ? (1.0f / 128.0f) : (-1.0f / 128.0f));
        float gw = sw + (((rc & 1) != 0) ? (1.0f / 128.0f) : (-1.0f / 128.0f));
        const float lim = 1.0f - 1e-6f;
        gh = fminf(fmaxf(gh, -lim), lim);
        gw = fminf(fmaxf(gw, -lim), lim);
        int iy = (int)rintf(((gh + 1.0f) * 128.0f - 1.0f) * 0.5f);  // round-half-even
        int ix = (int)rintf(((gw + 1.0f) * 128.0f - 1.0f) * 0.5f);
        iy = iy < 0 ? 0 : (iy > 127 ? 127 : iy);
        ix = ix < 0 ? 0 : (ix > 127 ? 127 : ix);
        float cy = (iy + 0.5f) * (2.0f / 128.0f) - 1.0f;
        float cx = (ix + 0.5f) * (2.0f / 128.0f) - 1.0f;
        float rh = (sh - cy) * 128.0f;
        float rw = (sw - cx) * 128.0f;
        sCell[t] = (iy << 7) + ix;
        sRelH[t] = rh; sRelW[t] = rw;
        sArea[t] = fabsf(rh * rw);
    }
    if (t < 256) {
        sWh[t] = mw0[576 * 256 + t];
        sWw[t] = mw0[577 * 256 + t];
    }
    __syncthreads();

    int wave = t >> 6, lane = t & 63, q = lane >> 4, r = lane & 15;

    // layer 1: lane-linear staging. Thread handles sample s = (wave&3)*16 + r,
    // feature half fbase = (wave>>2)*128, f = fbase + j*32 + q*8 .. +8, j=0..3.
    // Write chunk = (s>>4)*8 + (f>>5) = (wave&3)*8 + (wave>>2)*4 + j.
    {
        int s = ((wave & 3) << 4) + r;
        float rh = sRelH[s], rw = sRelW[s];
        int fbase = (wave >> 2) << 7;
        const float* ap = apre + ((size_t)sCell[s] << 8) + fbase + (q << 3);
        #pragma unroll
        for (int j = 0; j < 4; ++j) {
            int f0 = fbase + (j << 5) + (q << 3);
            float4v lo = *(const float4v*)(ap + (j << 5));
            float4v hi = *(const float4v*)(ap + (j << 5) + 4);
            half8 hv;
            #pragma unroll
            for (int kk = 0; kk < 4; ++kk) {
                float v = lo[kk] + rh * sWh[f0 + kk] + rw * sWw[f0 + kk];
                hv[kk] = (_Float16)fmaxf(v, 0.0f);
            }
            #pragma unroll
            for (int kk = 0; kk < 4; ++kk) {
                float v = hi[kk] + rh * sWh[f0 + 4 + kk] + rw * sWw[f0 + 4 + kk];
                hv[4 + kk] = (_Float16)fmaxf(v, 0.0f);
            }
            *(half8*)(act + ((((wave & 3) * 8 + (wave >> 2) * 4 + j) * 64 + lane) << 3)) = hv;
        }
    }
    __syncthreads();

    // hidden layers: wave owns out-features [wave*32, +32) x 64 samples
    float4v acc[2][4];
    #pragma unroll 1
    for (int l = 0; l < 3; ++l) {
        #pragma unroll
        for (int mti = 0; mti < 2; ++mti)
            #pragma unroll
            for (int nts = 0; nts < 4; ++nts)
                acc[mti][nts] = (float4v){0.f, 0.f, 0.f, 0.f};
        const _Float16* pw = pwm + l * 65536;
        for (int kc = 0; kc < 8; ++kc) {
            half8 Bf[4];
            #pragma unroll
            for (int nts = 0; nts < 4; ++nts)
                Bf[nts] = *(const half8*)(act + ((((nts << 3) + kc) * 64 + lane) << 3));
            #pragma unroll
            for (int mti = 0; mti < 2; ++mti) {
                half8 A = *(const half8*)(pw + ((((wave * 2 + mti) * 8 + kc) * 64 + lane) << 3));
                #pragma unroll
                for (int nts = 0; nts < 4; ++nts)
                    acc[mti][nts] = __builtin_amdgcn_mfma_f32_16x16x32_f16(
                        A, Bf[nts], acc[mti][nts], 0, 0, 0);
            }
        }
        const float* mb = (l == 0) ? mb1 : ((l == 1) ? mb2 : mb3);
        __syncthreads();   // all waves done reading act
        #pragma unroll
        for (int mti = 0; mti < 2; ++mti) {
            float4v bvv = *(const float4v*)(mb + (wave << 5) + mti * 16 + (q << 2));
            #pragma unroll
            for (int nts = 0; nts < 4; ++nts) {
                // f = wave*32 + mti*16 + q*4 + reg, s = nts*16 + r
                // chunk = nts*8 + wave (f>>5 == wave); pos = (mti*2+(q>>1))*16 + r;
                // elem = (q&1)*4 + reg  -> contiguous half4, lane-bijective.
                int base = ((((nts << 3) + wave) * 64
                             + ((mti * 2 + (q >> 1)) << 4) + r) << 3) + ((q & 1) << 2);
                half4 hv;
                #pragma unroll
                for (int reg = 0; reg < 4; ++reg)
                    hv[reg] = (_Float16)fmaxf(acc[mti][nts][reg] + bvv[reg], 0.0f);
                *(half4*)(act + base) = hv;
            }
        }
        __syncthreads();
    }

    // final layer: waves 0..3 handle samples [w*16, w*16+16); waves 4..7 idle
    if (wave < 4) {
        float4v af = {0.f, 0.f, 0.f, 0.f};
        #pragma unroll
        for (int kc = 0; kc < 8; ++kc) {
            half8 A = *(const half8*)(pw4 + ((kc * 64 + lane) << 3));
            half8 Bf = *(const half8*)(act + ((((wave << 3) + kc) * 64 + lane) << 3));
            af = __builtin_amdgcn_mfma_f32_16x16x32_f16(A, Bf, af, 0, 0, 0);
        }
        // lane (q=0, r): af[reg] = pred[ch=reg][sample = wave*16 + r]
        int s = (wave << 4) + r;
        int lp = s >> 2, rc = s & 3;
        float ar = sArea[(lp << 2) + (3 - rc)];    // LIIF diagonal-swapped area
        float c0 = (af[0] + mb4[0]) * ar;
        float c1 = (af[1] + mb4[1]) * ar;
        float c2 = (af[2] + mb4[2]) * ar;
        c0 += __shfl_xor(c0, 1); c1 += __shfl_xor(c1, 1); c2 += __shfl_xor(c2, 1);
        float at = ar + __shfl_xor(ar, 1);
        c0 += __shfl_xor(c0, 2); c1 += __shfl_xor(c1, 2); c2 += __shfl_xor(c2, 2);
        at += __shfl_xor(at, 2);
        if (q == 0 && rc == 0) {
            float inv = 1.0f / (at + 1e-9f);
            out[p0 + lp]          = fminf(fmaxf(c0 * inv, 0.0f), 1.0f);
            out[262144 + p0 + lp] = fminf(fmaxf(c1 * inv, 0.0f), 1.0f);
            out[524288 + p0 + lp] = fminf(fmaxf(c2 * inv, 0.0f), 1.0f);
        }
    }
}

extern "C" void kernel_launch(void* const* d_in, const int* in_sizes, int n_in,
                              void* d_out, int out_size, void* d_ws, size_t ws_size,
                              hipStream_t stream) {
    (void)in_sizes; (void)n_in; (void)out_size; (void)ws_size;
    const float* x      = (const float*)d_in[0];
    const float* head_w = (const float*)d_in[2];
    const float* head_b = (const float*)d_in[3];
    const float* rb_w   = (const float*)d_in[4];
    const float* rb_b   = (const float*)d_in[5];
    const float* tail_w = (const float*)d_in[6];
    const float* tail_b = (const float*)d_in[7];
    const float* mw0    = (const float*)d_in[8];
    const float* mb0    = (const float*)d_in[9];
    const float* mw1    = (const float*)d_in[10];
    const float* mb1    = (const float*)d_in[11];
    const float* mw2    = (const float*)d_in[12];
    const float* mb2    = (const float*)d_in[13];
    const float* mw3    = (const float*)d_in[14];
    const float* mb3    = (const float*)d_in[15];
    const float* mw4    = (const float*)d_in[16];
    const float* mb4    = (const float*)d_in[17];
    float* out = (float*)d_out;

    char* w = (char*)d_ws;
    auto take = [&](size_t n) { char* p = w; w += (n + 255) & ~(size_t)255; return p; };
    _Float16* pwc  = (_Float16*)take(33u * 36864u * 2u);
    _Float16* pw0  = (_Float16*)take(147456u * 2u);
    _Float16* pwm  = (_Float16*)take(200704u * 2u);
    float*    b0p  = (float*)take(256u * 4u);
    _Float16* h0   = (_Float16*)take((size_t)NPIX * 64u * 2u);
    _Float16* hbuf = (_Float16*)take((size_t)NPIX * 64u * 2u);
    _Float16* tbuf = (_Float16*)take((size_t)NPIX * 64u * 2u);
    _Float16* feat = (_Float16*)take((size_t)NPIX * 64u * 2u);
    float*    apre = (float*)take((size_t)NPIX * 256u * 4u);

    pack_all<<<10209, 256, 0, stream>>>(rb_w, tail_w, mw0, mw1, mw2, mw3, mw4, mb0,
                                        x, head_w, head_b, pwc, pw0, pwm, b0p, h0);

    const _Float16* cur = h0;
    for (int p = 0; p < 8; ++p) {
        _Float16* dst = (p & 1) ? tbuf : hbuf;
        rb_pair<<<512, 256, 0, stream>>>(cur, pwc + 4 * p * 36864, rb_b + p * 256, dst);
        cur = dst;
    }
    conv_mfma_r<4, 2, false, true, false><<<512, 256, 0, stream>>>(
        cur, pwc + 32 * 36864, tail_b, h0, feat, nullptr);
    conv_mfma_r<16, 4, false, false, true><<<1024, 256, 0, stream>>>(
        feat, pw0, b0p, nullptr, nullptr, apre);

    mlp_kernel<<<16384, 512, 0, stream>>>(apre, mw0, mb1, mb2, mb3, mb4,
                                          pwm, pwm + 196608, out);
}

// Round 12
// 755.320 us; speedup vs baseline: 1.0918x; 1.0756x over previous
//
#include <hip/hip_runtime.h>
#include <hip/hip_fp16.h>

typedef __attribute__((ext_vector_type(8))) _Float16 half8;
typedef __attribute__((ext_vector_type(4))) _Float16 half4;
typedef __attribute__((ext_vector_type(4))) float float4v;

#define NPIX 16384  // 128*128

__device__ inline half8 h8zero() {
    half8 z = {(_Float16)0, (_Float16)0, (_Float16)0, (_Float16)0,
               (_Float16)0, (_Float16)0, (_Float16)0, (_Float16)0};
    return z;
}

// ---------------- all weight packing + head conv in ONE dispatch ----------------
__global__ void pack_all(const float* __restrict__ rb_w, const float* __restrict__ tail_w,
                         const float* __restrict__ mw0, const float* __restrict__ mw1,
                         const float* __restrict__ mw2, const float* __restrict__ mw3,
                         const float* __restrict__ mw4, const float* __restrict__ mb0,
                         const float* __restrict__ x, const float* __restrict__ head_w,
                         const float* __restrict__ head_b,
                         _Float16* __restrict__ pwc, _Float16* __restrict__ pw0,
                         _Float16* __restrict__ pwm, float* __restrict__ b0p,
                         _Float16* __restrict__ h0) {
    int idx = blockIdx.x * 256 + threadIdx.x;
    if (idx < 1216512) {                      // conv weights -> B-frag order
        int ci = idx / 36864;
        int e  = idx % 36864;
        int j = e & 7, ln = (e >> 3) & 63, kcnt = e >> 9;
        int kc = kcnt % 18, ntc = kcnt / 18;
        int k = kc * 32 + (ln >> 4) * 8 + j;
        int nn = ntc * 16 + (ln & 15);
        int ij = k >> 6, c = k & 63;
        const float* src = (ci < 32) ? (rb_w + ci * 36864) : tail_w;
        pwc[idx] = (_Float16)src[(nn * 64 + c) * 9 + ij];
        return;
    }
    idx -= 1216512;
    if (idx < 147456) {                       // mw0[:576] pack (N=256)
        int j = idx & 7, ln = (idx >> 3) & 63, kcnt = idx >> 9;
        int kc = kcnt % 18, ntc = kcnt / 18;
        int k = kc * 32 + (ln >> 4) * 8 + j;
        int nn = ntc * 16 + (ln & 15);
        int ij = k >> 6, c = k & 63;
        pw0[idx] = (_Float16)mw0[(c * 9 + ij) * 256 + nn];
        return;
    }
    idx -= 147456;
    if (idx < 200704) {                       // mlp hidden + padded mw4
        if (idx < 196608) {
            int l = idx / 65536;
            int e = idx % 65536;
            int j = e & 7, ln = (e >> 3) & 63, kcnt = e >> 9;
            int kc = kcnt & 7, ntc = kcnt >> 3;
            int k = kc * 32 + (ln >> 4) * 8 + j;
            int nn = ntc * 16 + (ln & 15);
            const float* w = (l == 0) ? mw1 : ((l == 1) ? mw2 : mw3);
            pwm[idx] = (_Float16)w[k * 256 + nn];
        } else {
            int e = idx - 196608;
            int j = e & 7, ln = (e >> 3) & 63, kc = e >> 9;
            int k = kc * 32 + (ln >> 4) * 8 + j;
            int nn = ln & 15;
            pwm[idx] = (nn < 3) ? (_Float16)mw4[k * 3 + nn] : (_Float16)0.0f;
        }
        return;
    }
    idx -= 200704;
    if (idx < 256) {
        b0p[idx] = mb0[idx] + 0.5f * (mw0[578 * 256 + idx] + mw0[579 * 256 + idx]);
        return;
    }
    idx -= 256;
    if (idx < NPIX * 64) {                    // head conv (Cin=3, direct fp32)
        int o = idx & 63, p = idx >> 6;
        int py = p >> 7, px = p & 127;
        float acc = head_b[o];
        #pragma unroll
        for (int c = 0; c < 3; ++c)
            #pragma unroll
            for (int i = 0; i < 3; ++i)
                #pragma unroll
                for (int jj = 0; jj < 3; ++jj) {
                    int y = py + i - 1, xx = px + jj - 1;
                    if (y >= 0 && y < 128 && xx >= 0 && xx < 128)
                        acc += x[c * 16384 + y * 128 + xx]
                             * head_w[((o * 3 + c) * 3 + i) * 3 + jj];
                }
        h0[idx] = (_Float16)acc;
    }
}

// ---------------- fused 2-resblock kernel ----------------
#define LDS_STRIDE 72

template <int DH, int DW, int SW, int SOFF, int RES>
__device__ __forceinline__ void conv_stage(
    const _Float16* __restrict__ src, _Float16* __restrict__ dst, _Float16* __restrict__ INb,
    const _Float16* __restrict__ pw, const float* __restrict__ bias,
    int q, int r, int nb, int gy0, int gx0, _Float16* __restrict__ gout)
{
    half8 B[18];
    #pragma unroll
    for (int kc = 0; kc < 18; ++kc)
        B[kc] = *(const half8*)(pw + ((((nb >> 4) * 18 + kc) * 64 + (q << 4) + r) << 3));
    float bv = bias[nb + r];
    constexpr int NPXc = DH * DW;
    constexpr int NT = (NPXc + 15) >> 4;
    #pragma unroll 1
    for (int tl = 0; tl < NT; ++tl) {
        int pa = tl * 16 + r;
        int ca = pa < NPXc ? pa : NPXc - 1;
        int my = ca / DW, mx = ca % DW;
        float4v acc = {0.f, 0.f, 0.f, 0.f};
        #pragma unroll
        for (int kc = 0; kc < 18; ++kc) {
            int ij = kc >> 1;
            int di = ij / 3 - 1;
            int dj = ij % 3 - 1;
            int cb = ((kc & 1) << 5) + (q << 3);
            int sp = (my + 1 + di + SOFF) * SW + (mx + 1 + dj + SOFF);
            half8 a = *(const half8*)(src + sp * LDS_STRIDE + cb);
            acc = __builtin_amdgcn_mfma_f32_16x16x32_f16(a, B[kc], acc, 0, 0, 0);
        }
        #pragma unroll
        for (int reg = 0; reg < 4; ++reg) {
            int pc = tl * 16 + (q << 2) + reg;
            if (pc >= NPXc) continue;
            int dy = pc / DW, dx = pc % DW;
            int gy = gy0 + dy, gx = gx0 + dx;
            bool valid = (gy >= 0 && gy < 128 && gx >= 0 && gx < 128);
            if (RES == 0) {
                float v = fmaxf(acc[reg] + bv, 0.f);
                dst[pc * LDS_STRIDE + nb + r] = valid ? (_Float16)v : (_Float16)0.0f;
            } else if (RES == 1) {
                int sl = ((dy + 2) * 16 + dx + 2) * LDS_STRIDE + nb + r;
                float v = acc[reg] + bv + (float)INb[sl];
                INb[sl] = valid ? (_Float16)v : (_Float16)0.0f;
            } else {
                int sl = ((dy + 4) * 16 + dx + 4) * LDS_STRIDE + nb + r;
                float v = acc[reg] + bv + (float)INb[sl];
                gout[(((gy << 7) + gx) << 6) + nb + r] = (_Float16)v;
            }
        }
    }
}

__global__ __launch_bounds__(256, 3)
void rb_pair(const _Float16* __restrict__ img, const _Float16* __restrict__ pw,
             const float* __restrict__ bias, _Float16* __restrict__ out) {
    __shared__ _Float16 IN[192 * LDS_STRIDE];
    __shared__ _Float16 MID[140 * LDS_STRIDE];
    int t = threadIdx.x;
    int wave = t >> 6, lane = t & 63, q = lane >> 4, r = lane & 15;
    int tr = blockIdx.x >> 4, tc = blockIdx.x & 15;
    int ty0 = tr << 2, tx0 = tc << 3;
    int nb = wave << 4;

    #pragma unroll
    for (int i = 0; i < 6; ++i) {
        int idx = t + i * 256;
        int px = idx >> 3, c = idx & 7;
        int iy = px >> 4, ix = px & 15;
        int gy = ty0 - 4 + iy, gx = tx0 - 4 + ix;
        half8 v = h8zero();
        if (gy >= 0 && gy < 128 && gx >= 0 && gx < 128)
            v = *(const half8*)(img + (((gy << 7) + gx) << 6) + (c << 3));
        *(half8*)(IN + px * LDS_STRIDE + (c << 3)) = v;
    }
    __syncthreads();

    conv_stage<10, 14, 16, 0, 0>(IN, MID, IN, pw, bias, q, r, nb, ty0 - 3, tx0 - 3, nullptr);
    __syncthreads();
    conv_stage<8, 12, 14, 0, 1>(MID, nullptr, IN, pw + 36864, bias + 64, q, r, nb,
                                ty0 - 2, tx0 - 2, nullptr);
    __syncthreads();
    conv_stage<6, 10, 16, 2, 0>(IN, MID, IN, pw + 2 * 36864, bias + 128, q, r, nb,
                                ty0 - 1, tx0 - 1, nullptr);
    __syncthreads();
    conv_stage<4, 8, 10, 0, 2>(MID, nullptr, IN, pw + 3 * 36864, bias + 192, q, r, nb,
                               ty0, tx0, out);
}

// ---------------- unfused conv (tail + stage-A) ----------
template <int NTOT, int MTPER, bool RELU, bool RES, bool F32OUT>
__global__ __launch_bounds__(256, 2)
void conv_mfma_r(const _Float16* __restrict__ img, const _Float16* __restrict__ pw,
                 const float* __restrict__ bias, const _Float16* res,
                 _Float16* outh, float* outf) {
    int wave = threadIdx.x >> 6, lane = threadIdx.x & 63;
    int q = lane >> 4, r = lane & 15;
    int nt, mt0;
    if constexpr (NTOT == 4) {
        nt = wave;
        mt0 = blockIdx.x * MTPER;
    } else {
        nt = (blockIdx.x & 3) * 4 + wave;
        mt0 = (blockIdx.x >> 2) * MTPER;
    }
    half8 B[18];
    #pragma unroll
    for (int kc = 0; kc < 18; ++kc)
        B[kc] = *(const half8*)(pw + (((nt * 18 + kc) * 64 + lane) << 3));
    int n = nt * 16 + r;
    float bv = bias[n];
    #pragma unroll
    for (int mi = 0; mi < MTPER; ++mi) {
        int mt = mt0 + mi;
        int p0 = mt * 16;
        int py = p0 >> 7;
        int pxl = (p0 & 127) + r;
        float4v acc = {0.f, 0.f, 0.f, 0.f};
        #pragma unroll
        for (int kc = 0; kc < 18; ++kc) {
            int ij = kc >> 1;
            int di = ij / 3 - 1;
            int dj = ij % 3 - 1;
            int cb = ((kc & 1) << 5) + (q << 3);
            int yy = py + di, xx = pxl + dj;
            half8 a = h8zero();
            if (yy >= 0 && yy < 128 && xx >= 0 && xx < 128)
                a = *(const half8*)(img + (((yy << 7) + xx) << 6) + cb);
            acc = __builtin_amdgcn_mfma_f32_16x16x32_f16(a, B[kc], acc, 0, 0, 0);
        }
        #pragma unroll
        for (int reg = 0; reg < 4; ++reg) {
            int p = p0 + (q << 2) + reg;
            float v = acc[reg] + bv;
            if (RES) v += (float)res[p * (NTOT * 16) + n];
            if (RELU) v = fmaxf(v, 0.f);
            if (F32OUT) outf[p * (NTOT * 16) + n] = v;
            else        outh[p * (NTOT * 16) + n] = (_Float16)v;
        }
    }
}

// ---------------- fused LIIF MLP + ensembling (32 px, 8-wave transposed) --------
// Block: 512 thr (8 waves) = 32 output pixels = 128 samples.
// Transposed MFMA: M = out-features, N = samples. Wave w owns features
// [w*32, +32) x all 128 samples -> acc[2][8] = 64 AGPR. Unified-file budget:
// 64 arch + 64 acc = 128/thread -> 4 waves/SIMD under launch_bounds(512,4).
// Weight reads amortize over 128 samples (2x R4/R11): per-CU weight traffic
// ~12 MB (~91 us) drops below the 203 us MFMA floor.
// act LDS fragment-major: chunk X = (s>>4)*8 + (f>>5); within chunk lane (q,r)
// elem e: entity (s>>4)*16+r, element (f>>5)*32 + q*8 + e. Role-symmetric.
__global__ __launch_bounds__(512, 4)
void mlp_kernel(const float* __restrict__ apre, const float* __restrict__ mw0,
                const float* __restrict__ mb1, const float* __restrict__ mb2,
                const float* __restrict__ mb3, const float* __restrict__ mb4,
                const _Float16* __restrict__ pwm, const _Float16* __restrict__ pw4,
                float* __restrict__ out) {
    __shared__ _Float16 act[32768];        // 128 samples x 256 features (64 KB)
    __shared__ float sArea[128], sRelH[128], sRelW[128];
    __shared__ int sCell[128];
    __shared__ float sWh[256], sWw[256];

    int t = threadIdx.x;
    int bid = blockIdx.x;
    int logical = (bid & 7) * 1024 + (bid >> 3);   // XCD-contiguous pixel strips
    int p0 = logical << 5;                          // 32 pixels per block

    if (t < 128) {
        int lp = t >> 2, rc = t & 3;
        int p = p0 + lp;
        int oh = p >> 9, ow = p & 511;
        float sh = (oh + 0.5f) * (2.0f / 512.0f) - 1.0f;
        float sw = (ow + 0.5f) * (2.0f / 512.0f) - 1.0f;
        float gh = sh + (((rc >> 1) != 0) ? (1.0f / 128.0f) : (-1.0f / 128.0f));
        float gw = sw + (((rc & 1) != 0) ? (1.0f / 128.0f) : (-1.0f / 128.0f));
        const float lim = 1.0f - 1e-6f;
        gh = fminf(fmaxf(gh, -lim), lim);
        gw = fminf(fmaxf(gw, -lim), lim);
        int iy = (int)rintf(((gh + 1.0f) * 128.0f - 1.0f) * 0.5f);  // round-half-even
        int ix = (int)rintf(((gw + 1.0f) * 128.0f - 1.0f) * 0.5f);
        iy = iy < 0 ? 0 : (iy > 127 ? 127 : iy);
        ix = ix < 0 ? 0 : (ix > 127 ? 127 : ix);
        float cy = (iy + 0.5f) * (2.0f / 128.0f) - 1.0f;
        float cx = (ix + 0.5f) * (2.0f / 128.0f) - 1.0f;
        float rh = (sh - cy) * 128.0f;
        float rw = (sw - cx) * 128.0f;
        sCell[t] = (iy << 7) + ix;
        sRelH[t] = rh; sRelW[t] = rw;
        sArea[t] = fabsf(rh * rw);
    }
    if (t < 256) {
        sWh[t] = mw0[576 * 256 + t];
        sWw[t] = mw0[577 * 256 + t];
    }
    __syncthreads();

    int wave = t >> 6, lane = t & 63, q = lane >> 4, r = lane & 15;

    // layer 1: lane-linear staging. Thread handles sample s = wave*16 + r,
    // features f = j*32 + q*8 .. +8, j = 0..7. Write chunk = wave*8 + j.
    {
        int s = (wave << 4) + r;
        float rh = sRelH[s], rw = sRelW[s];
        const float* ap = apre + ((size_t)sCell[s] << 8) + (q << 3);
        #pragma unroll
        for (int j = 0; j < 8; ++j) {
            int f0 = (j << 5) + (q << 3);
            float4v lo = *(const float4v*)(ap + (j << 5));
            float4v hi = *(const float4v*)(ap + (j << 5) + 4);
            half8 hv;
            #pragma unroll
            for (int kk = 0; kk < 4; ++kk) {
                float v = lo[kk] + rh * sWh[f0 + kk] + rw * sWw[f0 + kk];
                hv[kk] = (_Float16)fmaxf(v, 0.0f);
            }
            #pragma unroll
            for (int kk = 0; kk < 4; ++kk) {
                float v = hi[kk] + rh * sWh[f0 + 4 + kk] + rw * sWw[f0 + 4 + kk];
                hv[4 + kk] = (_Float16)fmaxf(v, 0.0f);
            }
            *(half8*)(act + ((((wave << 3) + j) * 64 + lane) << 3)) = hv;
        }
    }
    __syncthreads();

    // hidden layers: wave owns out-features [wave*32, +32) x 128 samples.
    // Per kc: A0,A1 loaded once; Bf[4] reused for sample-halves (register shave).
    float4v acc[2][8];
    #pragma unroll 1
    for (int l = 0; l < 3; ++l) {
        #pragma unroll
        for (int mti = 0; mti < 2; ++mti)
            #pragma unroll
            for (int nts = 0; nts < 8; ++nts)
                acc[mti][nts] = (float4v){0.f, 0.f, 0.f, 0.f};
        const _Float16* pw = pwm + l * 65536;
        for (int kc = 0; kc < 8; ++kc) {
            half8 A0 = *(const half8*)(pw + ((((wave * 2 + 0) * 8 + kc) * 64 + lane) << 3));
            half8 A1 = *(const half8*)(pw + ((((wave * 2 + 1) * 8 + kc) * 64 + lane) << 3));
            half8 Bf[4];
            #pragma unroll
            for (int nts = 0; nts < 4; ++nts)
                Bf[nts] = *(const half8*)(act + ((((nts << 3) + kc) * 64 + lane) << 3));
            #pragma unroll
            for (int nts = 0; nts < 4; ++nts) {
                acc[0][nts] = __builtin_amdgcn_mfma_f32_16x16x32_f16(A0, Bf[nts], acc[0][nts], 0, 0, 0);
                acc[1][nts] = __builtin_amdgcn_mfma_f32_16x16x32_f16(A1, Bf[nts], acc[1][nts], 0, 0, 0);
            }
            #pragma unroll
            for (int nts = 0; nts < 4; ++nts)
                Bf[nts] = *(const half8*)(act + (((((nts + 4) << 3) + kc) * 64 + lane) << 3));
            #pragma unroll
            for (int nts = 0; nts < 4; ++nts) {
                acc[0][nts + 4] = __builtin_amdgcn_mfma_f32_16x16x32_f16(A0, Bf[nts], acc[0][nts + 4], 0, 0, 0);
                acc[1][nts + 4] = __builtin_amdgcn_mfma_f32_16x16x32_f16(A1, Bf[nts], acc[1][nts + 4], 0, 0, 0);
            }
        }
        const float* mb = (l == 0) ? mb1 : ((l == 1) ? mb2 : mb3);
        __syncthreads();   // all waves done reading act
        #pragma unroll
        for (int mti = 0; mti < 2; ++mti) {
            float4v bvv = *(const float4v*)(mb + (wave << 5) + mti * 16 + (q << 2));
            #pragma unroll
            for (int nts = 0; nts < 8; ++nts) {
                // f = wave*32 + mti*16 + q*4 + reg, s = nts*16 + r
                // chunk = nts*8 + wave; q' = mti*2 + (q>>1); elem = (q&1)*4 + reg
                int base = ((((nts << 3) + wave) * 64
                             + ((mti * 2 + (q >> 1)) << 4) + r) << 3) + ((q & 1) << 2);
                half4 hv;
                #pragma unroll
                for (int reg = 0; reg < 4; ++reg)
                    hv[reg] = (_Float16)fmaxf(acc[mti][nts][reg] + bvv[reg], 0.0f);
                *(half4*)(act + base) = hv;
            }
        }
        __syncthreads();
    }

    // final layer: wave w handles samples [w*16, w*16+16) (all 8 waves active)
    {
        float4v af = {0.f, 0.f, 0.f, 0.f};
        #pragma unroll
        for (int kc = 0; kc < 8; ++kc) {
            half8 A = *(const half8*)(pw4 + ((kc * 64 + lane) << 3));
            half8 Bf = *(const half8*)(act + ((((wave << 3) + kc) * 64 + lane) << 3));
            af = __builtin_amdgcn_mfma_f32_16x16x32_f16(A, Bf, af, 0, 0, 0);
        }
        // lane (q=0, r): af[reg] = pred[ch=reg][sample = wave*16 + r]
        int s = (wave << 4) + r;
        int lp = s >> 2, rc = s & 3;
        float ar = sArea[(lp << 2) + (3 - rc)];    // LIIF diagonal-swapped area
        float c0 = (af[0] + mb4[0]) * ar;
        float c1 = (af[1] + mb4[1]) * ar;
        float c2 = (af[2] + mb4[2]) * ar;
        c0 += __shfl_xor(c0, 1); c1 += __shfl_xor(c1, 1); c2 += __shfl_xor(c2, 1);
        float at = ar + __shfl_xor(ar, 1);
        c0 += __shfl_xor(c0, 2); c1 += __shfl_xor(c1, 2); c2 += __shfl_xor(c2, 2);
        at += __shfl_xor(at, 2);
        if (q == 0 && rc == 0) {
            float inv = 1.0f / (at + 1e-9f);
            out[p0 + lp]          = fminf(fmaxf(c0 * inv, 0.0f), 1.0f);
            out[262144 + p0 + lp] = fminf(fmaxf(c1 * inv, 0.0f), 1.0f);
            out[524288 + p0 + lp] = fminf(fmaxf(c2 * inv, 0.0f), 1.0f);
        }
    }
}

extern "C" void kernel_launch(void* const* d_in, const int* in_sizes, int n_in,
                              void* d_out, int out_size, void* d_ws, size_t ws_size,
                              hipStream_t stream) {
    (void)in_sizes; (void)n_in; (void)out_size; (void)ws_size;
    const float* x      = (const float*)d_in[0];
    const float* head_w = (const float*)d_in[2];
    const float* head_b = (const float*)d_in[3];
    const float* rb_w   = (const float*)d_in[4];
    const float* rb_b   = (const float*)d_in[5];
    const float* tail_w = (const float*)d_in[6];
    const float* tail_b = (const float*)d_in[7];
    const float* mw0    = (const float*)d_in[8];
    const float* mb0    = (const float*)d_in[9];
    const float* mw1    = (const float*)d_in[10];
    const float* mb1    = (const float*)d_in[11];
    const float* mw2    = (const float*)d_in[12];
    const float* mb2    = (const float*)d_in[13];
    const float* mw3    = (const float*)d_in[14];
    const float* mb3    = (const float*)d_in[15];
    const float* mw4    = (const float*)d_in[16];
    const float* mb4    = (const float*)d_in[17];
    float* out = (float*)d_out;

    char* w = (char*)d_ws;
    auto take = [&](size_t n) { char* p = w; w += (n + 255) & ~(size_t)255; return p; };
    _Float16* pwc  = (_Float16*)take(33u * 36864u * 2u);
    _Float16* pw0  = (_Float16*)take(147456u * 2u);
    _Float16* pwm  = (_Float16*)take(200704u * 2u);
    float*    b0p  = (float*)take(256u * 4u);
    _Float16* h0   = (_Float16*)take((size_t)NPIX * 64u * 2u);
    _Float16* hbuf = (_Float16*)take((size_t)NPIX * 64u * 2u);
    _Float16* tbuf = (_Float16*)take((size_t)NPIX * 64u * 2u);
    _Float16* feat = (_Float16*)take((size_t)NPIX * 64u * 2u);
    float*    apre = (float*)take((size_t)NPIX * 256u * 4u);

    pack_all<<<10209, 256, 0, stream>>>(rb_w, tail_w, mw0, mw1, mw2, mw3, mw4, mb0,
                                        x, head_w, head_b, pwc, pw0, pwm, b0p, h0);

    const _Float16* cur = h0;
    for (int p = 0; p < 8; ++p) {
        _Float16* dst = (p & 1) ? tbuf : hbuf;
        rb_pair<<<512, 256, 0, stream>>>(cur, pwc + 4 * p * 36864, rb_b + p * 256, dst);
        cur = dst;
    }
    conv_mfma_r<4, 2, false, true, false><<<512, 256, 0, stream>>>(
        cur, pwc + 32 * 36864, tail_b, h0, feat, nullptr);
    conv_mfma_r<16, 4, false, false, true><<<1024, 256, 0, stream>>>(
        feat, pw0, b0p, nullptr, nullptr, apre);

    mlp_kernel<<<8192, 512, 0, stream>>>(apre, mw0, mb1, mb2, mb3, mb4,
                                         pwm, pwm + 196608, out);
}